// Round 3
// baseline (1086.130 us; speedup 1.0000x reference)
//
#include <hip/hip_runtime.h>
#include <math.h>

#define BB 64
#define ID 10
#define MD 64
#define AD 16384
#define HCD 256
#define HRD 2
#define OD 8
#define PD 338
#define LIN 138
#define EPSF 1e-8f

// ---- output layout (floats), reference return order:
// logits[B,O], mem_new[B,M,A], rvs[B,HR,M], rws[B,HR,A], w_wr[B,A], h_new[B,HC], c_new[B,HC]
static constexpr size_t OFF_LOGITS = 0;
static constexpr size_t OFF_MEM = (size_t)BB * OD;
static constexpr size_t OFF_RVS = OFF_MEM + (size_t)BB * MD * AD;
static constexpr size_t OFF_RWS = OFF_RVS + (size_t)BB * HRD * MD;
static constexpr size_t OFF_WWR = OFF_RWS + (size_t)BB * HRD * AD;
static constexpr size_t OFF_H   = OFF_WWR + (size_t)BB * AD;
static constexpr size_t OFF_C   = OFF_H + (size_t)BB * HCD;

// ---- workspace layout (floats)
// per-b params (stride 384): [0:64) kn_w  [64:128) erase  [128:192) add
// [192:256) kn_r0  [256:320) kn_r1
// [320]=beta_w [321]=g_w [322..324]=s_w [325]=gamma_w
// [326..331]=read0 (beta,g,s0,s1,s2,gamma)  [332..337]=read1
static constexpr size_t PAR = 0;
static constexpr size_t PAR_STR = 384;
static constexpr size_t EW   = PAR + (size_t)BB * PAR_STR;
static constexpr size_t ER   = EW + (size_t)BB * AD;
static constexpr size_t SUMS = ER + (size_t)2 * BB * AD;   // per-b 8 slots

__device__ __forceinline__ float sigmoidf_(float x) { return 1.f / (1.f + expf(-x)); }
__device__ __forceinline__ float softplusf_(float x) { return x > 20.f ? x : log1pf(expf(x)); }

// ---------------------------------------------------------------------------
// K1: LSTM + interface + param processing (one block per batch, wave-coop dots)
// ---------------------------------------------------------------------------
__global__ __launch_bounds__(256) void k_small(
    const float* __restrict__ inputs, const float* __restrict__ read_vecs,
    const float* __restrict__ h, const float* __restrict__ c,
    const float* __restrict__ W_ih, const float* __restrict__ W_hh,
    const float* __restrict__ b_lstm, const float* __restrict__ W_int,
    const float* __restrict__ b_int, const float* __restrict__ W_out,
    const float* __restrict__ b_out, float* __restrict__ out,
    float* __restrict__ ws)
{
  const int b = blockIdx.x;
  const int t = threadIdx.x;
  const int lane = t & 63, wv = t >> 6;
  __shared__ float sx[LIN];
  __shared__ float sh[HCD];
  __shared__ float sg[4 * HCD];
  __shared__ float shn[HCD];
  __shared__ float sp[PD];

  if (t < ID) sx[t] = inputs[(size_t)b * ID + t];
  else if (t < LIN) sx[t] = read_vecs[(size_t)b * HRD * MD + (t - ID)];
  if (t < HCD) sh[t] = h[(size_t)b * HCD + t];
  if (t < HRD * MD) out[OFF_RVS + (size_t)b * HRD * MD + t] = 0.f;
  if (t >= 128 && t < 136) ws[SUMS + (size_t)b * 8 + (t - 128)] = 0.f;
  __syncthreads();

  // gates: wave wv handles outputs [wv*256, wv*256+256), lanes cooperate per output
  for (int jj = 0; jj < 256; ++jj) {
    const int j = wv * 256 + jj;
    float acc = 0.f;
    const float* wr = W_ih + (size_t)j * LIN;
    for (int k = lane; k < LIN; k += 64) acc += sx[k] * wr[k];
    const float* wh = W_hh + (size_t)j * HCD;
    #pragma unroll
    for (int kk = 0; kk < 4; ++kk) acc += sh[lane + kk * 64] * wh[lane + kk * 64];
    #pragma unroll
    for (int o = 32; o > 0; o >>= 1) acc += __shfl_xor(acc, o);
    if (lane == 0) sg[j] = acc + b_lstm[j];
  }
  __syncthreads();

  // LSTM elementwise (t indexes hidden channel)
  {
    float ig = sg[t], fg = sg[t + 256], gg = sg[t + 512], og = sg[t + 768];
    float cv = c[(size_t)b * HCD + t];
    float cn = sigmoidf_(fg) * cv + sigmoidf_(ig) * tanhf(gg);
    float hn = sigmoidf_(og) * tanhf(cn);
    shn[t] = hn;
    out[OFF_C + (size_t)b * HCD + t] = cn;
    out[OFF_H + (size_t)b * HCD + t] = hn;
  }
  __syncthreads();

  // p = h_new @ W_int.T + b_int  (wave-coop, wave handles j = wv, wv+4, ...)
  for (int j = wv; j < PD; j += 4) {
    float acc = 0.f;
    const float* wr = W_int + (size_t)j * HCD;
    #pragma unroll
    for (int kk = 0; kk < 4; ++kk) acc += shn[lane + kk * 64] * wr[lane + kk * 64];
    #pragma unroll
    for (int o = 32; o > 0; o >>= 1) acc += __shfl_xor(acc, o);
    if (lane == 0) sp[j] = acc + b_int[j];
  }
  // logits
  for (int j = wv; j < OD; j += 4) {
    float acc = 0.f;
    const float* wr = W_out + (size_t)j * HCD;
    #pragma unroll
    for (int kk = 0; kk < 4; ++kk) acc += shn[lane + kk * 64] * wr[lane + kk * 64];
    #pragma unroll
    for (int o = 32; o > 0; o >>= 1) acc += __shfl_xor(acc, o);
    if (lane == 0) out[OFF_LOGITS + (size_t)b * OD + j] = acc + b_out[j];
  }
  __syncthreads();

  // param processing
  float* par = ws + PAR + (size_t)b * PAR_STR;
  if (wv < 3) {
    // wv==0: write head (p base 140, kn slot 0); wv==1/2: read heads 0/1
    const int base = (wv == 0) ? 140 : (wv - 1) * 70;
    const int slot = (wv == 0) ? 0 : (192 + (wv - 1) * 64);
    float kv = sp[base + lane];
    float ss = kv * kv;
    #pragma unroll
    for (int o = 32; o > 0; o >>= 1) ss += __shfl_xor(ss, o);
    par[slot + lane] = kv / (sqrtf(ss) + EPSF);
    if (lane == 0) {
      const int sb = (wv == 0) ? 320 : (326 + (wv - 1) * 6);
      float beta = softplusf_(sp[base + 64]);
      float g = sigmoidf_(sp[base + 65]);
      float s0 = sp[base + 66], s1 = sp[base + 67], s2 = sp[base + 68];
      float mx = fmaxf(s0, fmaxf(s1, s2));
      float e0 = expf(s0 - mx), e1 = expf(s1 - mx), e2 = expf(s2 - mx);
      float inv = 1.f / (e0 + e1 + e2);
      float gamma = 1.f + softplusf_(sp[base + 69]);
      par[sb + 0] = beta; par[sb + 1] = g;
      par[sb + 2] = e0 * inv; par[sb + 3] = e1 * inv; par[sb + 4] = e2 * inv;
      par[sb + 5] = gamma;
    }
  } else {
    par[64 + lane] = sigmoidf_(sp[210 + lane]);   // erase
    par[128 + lane] = sp[274 + lane];             // add
  }
}

// ---------------------------------------------------------------------------
// Sweep geometry: grid (4, B), 512 threads. Block q owns columns
// [q*4096, (q+1)*4096): thread owns float4 at c0 = q*4096 + tid*4 and
// c1 = c0 + 2048. Per m-step a block reads 16KB contiguous.
// ---------------------------------------------------------------------------

// K2: write-head content sim over pre-update memory -> e = exp(beta*(sim-1))
__global__ __launch_bounds__(512) void k_wsim(const float* __restrict__ mem,
                                              float* __restrict__ ws)
{
  const int b = blockIdx.y, tid = threadIdx.x, q = blockIdx.x;
  const float* par = ws + PAR + (size_t)b * PAR_STR;
  __shared__ float kn[MD];
  if (tid < MD) kn[tid] = par[tid];
  __syncthreads();

  const size_t c0 = (size_t)q * 4096 + (size_t)tid * 4;
  const size_t c1 = c0 + 2048;
  const float* mb = mem + (size_t)b * MD * AD;

  float4 sA = {0,0,0,0}, sB = {0,0,0,0}, dA = {0,0,0,0}, dB = {0,0,0,0};
  #pragma unroll 4
  for (int m = 0; m < MD; ++m) {
    float4 vA = *(const float4*)(mb + (size_t)m * AD + c0);
    float4 vB = *(const float4*)(mb + (size_t)m * AD + c1);
    float kv = kn[m];
    sA.x += vA.x * vA.x; sA.y += vA.y * vA.y; sA.z += vA.z * vA.z; sA.w += vA.w * vA.w;
    sB.x += vB.x * vB.x; sB.y += vB.y * vB.y; sB.z += vB.z * vB.z; sB.w += vB.w * vB.w;
    dA.x += kv * vA.x;  dA.y += kv * vA.y;  dA.z += kv * vA.z;  dA.w += kv * vA.w;
    dB.x += kv * vB.x;  dB.y += kv * vB.y;  dB.z += kv * vB.z;  dB.w += kv * vB.w;
  }
  const float beta = par[320];
  float4 eA, eB;
  eA.x = expf(beta * (dA.x / (sqrtf(sA.x) + EPSF) - 1.f));
  eA.y = expf(beta * (dA.y / (sqrtf(sA.y) + EPSF) - 1.f));
  eA.z = expf(beta * (dA.z / (sqrtf(sA.z) + EPSF) - 1.f));
  eA.w = expf(beta * (dA.w / (sqrtf(sA.w) + EPSF) - 1.f));
  eB.x = expf(beta * (dB.x / (sqrtf(sB.x) + EPSF) - 1.f));
  eB.y = expf(beta * (dB.y / (sqrtf(sB.y) + EPSF) - 1.f));
  eB.z = expf(beta * (dB.z / (sqrtf(sB.z) + EPSF) - 1.f));
  eB.w = expf(beta * (dB.w / (sqrtf(sB.w) + EPSF) - 1.f));
  *(float4*)(ws + EW + (size_t)b * AD + c0) = eA;
  *(float4*)(ws + EW + (size_t)b * AD + c1) = eB;

  float s = eA.x + eA.y + eA.z + eA.w + eB.x + eB.y + eB.z + eB.w;
  #pragma unroll
  for (int o = 32; o > 0; o >>= 1) s += __shfl_xor(s, o);
  __shared__ float red[8];
  if ((tid & 63) == 0) red[tid >> 6] = s;
  __syncthreads();
  if (tid == 0) {
    float tot = 0.f;
    #pragma unroll
    for (int i = 0; i < 8; ++i) tot += red[i];
    atomicAdd(ws + SUMS + (size_t)b * 8 + 0, tot);
  }
}

// K3: write head: interpolate + circular shift + sharpen -> wp (unnormalized)
__global__ __launch_bounds__(256) void k_wsharp(const float* __restrict__ write_w,
                                                float* __restrict__ out,
                                                float* __restrict__ ws)
{
  const int b = blockIdx.y;
  const int tid = threadIdx.x;
  const int a0 = blockIdx.x * 1024 + tid * 4;
  const float* par = ws + PAR + (size_t)b * PAR_STR;
  const float g = par[321], s0 = par[322], s1 = par[323], s2 = par[324], gamma = par[325];
  const float inv_se = 1.f / ws[SUMS + (size_t)b * 8 + 0];
  const float* e = ws + EW + (size_t)b * AD;
  const float* wprev = write_w + (size_t)b * AD;

  float4 ec = *(const float4*)(e + a0);
  float4 wc = *(const float4*)(wprev + a0);
  const int am1 = (a0 - 1) & (AD - 1), ap4 = (a0 + 4) & (AD - 1);
  float ev[6] = {e[am1], ec.x, ec.y, ec.z, ec.w, e[ap4]};
  float wvv[6] = {wprev[am1], wc.x, wc.y, wc.z, wc.w, wprev[ap4]};
  float wg[6];
  #pragma unroll
  for (int i = 0; i < 6; ++i) wg[i] = g * ev[i] * inv_se + (1.f - g) * wvv[i];

  float4 wp;
  wp.x = powf(s0 * wg[2] + s1 * wg[1] + s2 * wg[0] + EPSF, gamma);
  wp.y = powf(s0 * wg[3] + s1 * wg[2] + s2 * wg[1] + EPSF, gamma);
  wp.z = powf(s0 * wg[4] + s1 * wg[3] + s2 * wg[2] + EPSF, gamma);
  wp.w = powf(s0 * wg[5] + s1 * wg[4] + s2 * wg[3] + EPSF, gamma);
  *(float4*)(out + OFF_WWR + (size_t)b * AD + a0) = wp;

  float s = wp.x + wp.y + wp.z + wp.w;
  #pragma unroll
  for (int o = 32; o > 0; o >>= 1) s += __shfl_xor(s, o);
  __shared__ float red[4];
  if ((tid & 63) == 0) red[tid >> 6] = s;
  __syncthreads();
  if (tid == 0) atomicAdd(ws + SUMS + (size_t)b * 8 + 1, red[0] + red[1] + red[2] + red[3]);
}

// K4: normalize w_wr, memory update, read-head sims over mem_new (fused)
__global__ __launch_bounds__(512) void k_update(const float* __restrict__ mem,
                                                float* __restrict__ out,
                                                float* __restrict__ ws)
{
  const int b = blockIdx.y, tid = threadIdx.x, q = blockIdx.x;
  const float* par = ws + PAR + (size_t)b * PAR_STR;
  __shared__ float se[MD], sa[MD], sk0[MD], sk1[MD];
  if (tid < MD) {
    se[tid] = par[64 + tid]; sa[tid] = par[128 + tid];
    sk0[tid] = par[192 + tid]; sk1[tid] = par[256 + tid];
  }
  __syncthreads();

  const size_t c0 = (size_t)q * 4096 + (size_t)tid * 4;
  const size_t c1 = c0 + 2048;
  const float invw = 1.f / (ws[SUMS + (size_t)b * 8 + 1] + EPSF);
  float* wwr = out + OFF_WWR + (size_t)b * AD;
  float4 wA = *(float4*)(wwr + c0);
  float4 wB = *(float4*)(wwr + c1);
  wA.x *= invw; wA.y *= invw; wA.z *= invw; wA.w *= invw;
  wB.x *= invw; wB.y *= invw; wB.z *= invw; wB.w *= invw;
  *(float4*)(wwr + c0) = wA;
  *(float4*)(wwr + c1) = wB;

  const float* mb = mem + (size_t)b * MD * AD;
  float* nb = out + OFF_MEM + (size_t)b * MD * AD;
  float4 sA = {0,0,0,0}, sB = {0,0,0,0};
  float4 d0A = {0,0,0,0}, d0B = {0,0,0,0}, d1A = {0,0,0,0}, d1B = {0,0,0,0};
  #pragma unroll 4
  for (int m = 0; m < MD; ++m) {
    float4 vA = *(const float4*)(mb + (size_t)m * AD + c0);
    float4 vB = *(const float4*)(mb + (size_t)m * AD + c1);
    float er = se[m], ad = sa[m], k0 = sk0[m], k1 = sk1[m];
    float4 nA, nB;
    nA.x = vA.x * (1.f - er * wA.x) + ad * wA.x;
    nA.y = vA.y * (1.f - er * wA.y) + ad * wA.y;
    nA.z = vA.z * (1.f - er * wA.z) + ad * wA.z;
    nA.w = vA.w * (1.f - er * wA.w) + ad * wA.w;
    nB.x = vB.x * (1.f - er * wB.x) + ad * wB.x;
    nB.y = vB.y * (1.f - er * wB.y) + ad * wB.y;
    nB.z = vB.z * (1.f - er * wB.z) + ad * wB.z;
    nB.w = vB.w * (1.f - er * wB.w) + ad * wB.w;
    *(float4*)(nb + (size_t)m * AD + c0) = nA;
    *(float4*)(nb + (size_t)m * AD + c1) = nB;
    sA.x += nA.x * nA.x; sA.y += nA.y * nA.y; sA.z += nA.z * nA.z; sA.w += nA.w * nA.w;
    sB.x += nB.x * nB.x; sB.y += nB.y * nB.y; sB.z += nB.z * nB.z; sB.w += nB.w * nB.w;
    d0A.x += k0 * nA.x; d0A.y += k0 * nA.y; d0A.z += k0 * nA.z; d0A.w += k0 * nA.w;
    d0B.x += k0 * nB.x; d0B.y += k0 * nB.y; d0B.z += k0 * nB.z; d0B.w += k0 * nB.w;
    d1A.x += k1 * nA.x; d1A.y += k1 * nA.y; d1A.z += k1 * nA.z; d1A.w += k1 * nA.w;
    d1B.x += k1 * nB.x; d1B.y += k1 * nB.y; d1B.z += k1 * nB.z; d1B.w += k1 * nB.w;
  }
  const float b0 = par[326], b1 = par[332];
  float4 e0A, e0B, e1A, e1B;
  e0A.x = expf(b0 * (d0A.x / (sqrtf(sA.x) + EPSF) - 1.f));
  e0A.y = expf(b0 * (d0A.y / (sqrtf(sA.y) + EPSF) - 1.f));
  e0A.z = expf(b0 * (d0A.z / (sqrtf(sA.z) + EPSF) - 1.f));
  e0A.w = expf(b0 * (d0A.w / (sqrtf(sA.w) + EPSF) - 1.f));
  e0B.x = expf(b0 * (d0B.x / (sqrtf(sB.x) + EPSF) - 1.f));
  e0B.y = expf(b0 * (d0B.y / (sqrtf(sB.y) + EPSF) - 1.f));
  e0B.z = expf(b0 * (d0B.z / (sqrtf(sB.z) + EPSF) - 1.f));
  e0B.w = expf(b0 * (d0B.w / (sqrtf(sB.w) + EPSF) - 1.f));
  e1A.x = expf(b1 * (d1A.x / (sqrtf(sA.x) + EPSF) - 1.f));
  e1A.y = expf(b1 * (d1A.y / (sqrtf(sA.y) + EPSF) - 1.f));
  e1A.z = expf(b1 * (d1A.z / (sqrtf(sA.z) + EPSF) - 1.f));
  e1A.w = expf(b1 * (d1A.w / (sqrtf(sA.w) + EPSF) - 1.f));
  e1B.x = expf(b1 * (d1B.x / (sqrtf(sB.x) + EPSF) - 1.f));
  e1B.y = expf(b1 * (d1B.y / (sqrtf(sB.y) + EPSF) - 1.f));
  e1B.z = expf(b1 * (d1B.z / (sqrtf(sB.z) + EPSF) - 1.f));
  e1B.w = expf(b1 * (d1B.w / (sqrtf(sB.w) + EPSF) - 1.f));
  float* er0 = ws + ER + ((size_t)0 * BB + b) * AD;
  float* er1 = ws + ER + ((size_t)1 * BB + b) * AD;
  *(float4*)(er0 + c0) = e0A; *(float4*)(er0 + c1) = e0B;
  *(float4*)(er1 + c0) = e1A; *(float4*)(er1 + c1) = e1B;

  float p0 = e0A.x + e0A.y + e0A.z + e0A.w + e0B.x + e0B.y + e0B.z + e0B.w;
  float p1 = e1A.x + e1A.y + e1A.z + e1A.w + e1B.x + e1B.y + e1B.z + e1B.w;
  #pragma unroll
  for (int o = 32; o > 0; o >>= 1) { p0 += __shfl_xor(p0, o); p1 += __shfl_xor(p1, o); }
  __shared__ float red[16];
  const int lane = tid & 63, wv = tid >> 6;
  if (lane == 0) { red[wv] = p0; red[8 + wv] = p1; }
  __syncthreads();
  if (tid == 0) {
    float t0 = 0.f, t1 = 0.f;
    #pragma unroll
    for (int i = 0; i < 8; ++i) { t0 += red[i]; t1 += red[8 + i]; }
    atomicAdd(ws + SUMS + (size_t)b * 8 + 2, t0);
    atomicAdd(ws + SUMS + (size_t)b * 8 + 3, t1);
  }
}

// K5: read heads: interpolate + shift + sharpen -> wp into rws slot
__global__ __launch_bounds__(256) void k_rsharp(const float* __restrict__ read_w,
                                                float* __restrict__ out,
                                                float* __restrict__ ws)
{
  const int b = blockIdx.y;
  const int hH = blockIdx.z;
  const int tid = threadIdx.x;
  const int a0 = blockIdx.x * 1024 + tid * 4;
  const float* par = ws + PAR + (size_t)b * PAR_STR;
  const int sb = 326 + hH * 6;
  const float g = par[sb + 1], s0 = par[sb + 2], s1 = par[sb + 3], s2 = par[sb + 4], gamma = par[sb + 5];
  const float inv_se = 1.f / ws[SUMS + (size_t)b * 8 + 2 + hH];
  const float* e = ws + ER + ((size_t)hH * BB + b) * AD;
  const float* wprev = read_w + ((size_t)b * HRD + hH) * AD;

  float4 ec = *(const float4*)(e + a0);
  float4 wc = *(const float4*)(wprev + a0);
  const int am1 = (a0 - 1) & (AD - 1), ap4 = (a0 + 4) & (AD - 1);
  float ev[6] = {e[am1], ec.x, ec.y, ec.z, ec.w, e[ap4]};
  float wvv[6] = {wprev[am1], wc.x, wc.y, wc.z, wc.w, wprev[ap4]};
  float wg[6];
  #pragma unroll
  for (int i = 0; i < 6; ++i) wg[i] = g * ev[i] * inv_se + (1.f - g) * wvv[i];

  float4 wp;
  wp.x = powf(s0 * wg[2] + s1 * wg[1] + s2 * wg[0] + EPSF, gamma);
  wp.y = powf(s0 * wg[3] + s1 * wg[2] + s2 * wg[1] + EPSF, gamma);
  wp.z = powf(s0 * wg[4] + s1 * wg[3] + s2 * wg[2] + EPSF, gamma);
  wp.w = powf(s0 * wg[5] + s1 * wg[4] + s2 * wg[3] + EPSF, gamma);
  *(float4*)(out + OFF_RWS + ((size_t)b * HRD + hH) * AD + a0) = wp;

  float s = wp.x + wp.y + wp.z + wp.w;
  #pragma unroll
  for (int o = 32; o > 0; o >>= 1) s += __shfl_xor(s, o);
  __shared__ float red[4];
  if ((tid & 63) == 0) red[tid >> 6] = s;
  __syncthreads();
  if (tid == 0) atomicAdd(ws + SUMS + (size_t)b * 8 + 4 + hH, red[0] + red[1] + red[2] + red[3]);
}

// K6: normalize rws in place + read vectors (one pass over mem_new)
__global__ __launch_bounds__(512) void k_rv(float* __restrict__ out,
                                            const float* __restrict__ ws)
{
  const int b = blockIdx.y, tid = threadIdx.x, q = blockIdx.x;
  const size_t c0 = (size_t)q * 4096 + (size_t)tid * 4;
  const size_t c1 = c0 + 2048;
  const float inv0 = 1.f / (ws[SUMS + (size_t)b * 8 + 4] + EPSF);
  const float inv1 = 1.f / (ws[SUMS + (size_t)b * 8 + 5] + EPSF);

  float* r0 = out + OFF_RWS + ((size_t)b * HRD + 0) * AD;
  float* r1 = out + OFF_RWS + ((size_t)b * HRD + 1) * AD;
  float4 w0A = *(float4*)(r0 + c0), w0B = *(float4*)(r0 + c1);
  float4 w1A = *(float4*)(r1 + c0), w1B = *(float4*)(r1 + c1);
  w0A.x *= inv0; w0A.y *= inv0; w0A.z *= inv0; w0A.w *= inv0;
  w0B.x *= inv0; w0B.y *= inv0; w0B.z *= inv0; w0B.w *= inv0;
  w1A.x *= inv1; w1A.y *= inv1; w1A.z *= inv1; w1A.w *= inv1;
  w1B.x *= inv1; w1B.y *= inv1; w1B.z *= inv1; w1B.w *= inv1;
  *(float4*)(r0 + c0) = w0A; *(float4*)(r0 + c1) = w0B;
  *(float4*)(r1 + c0) = w1A; *(float4*)(r1 + c1) = w1B;

  const float* mn = out + OFF_MEM + (size_t)b * MD * AD;
  __shared__ float part[8][MD][2];
  const int lane = tid & 63, wv = tid >> 6;
  for (int m = 0; m < MD; ++m) {
    float4 vA = *(const float4*)(mn + (size_t)m * AD + c0);
    float4 vB = *(const float4*)(mn + (size_t)m * AD + c1);
    float p0 = vA.x * w0A.x + vA.y * w0A.y + vA.z * w0A.z + vA.w * w0A.w
             + vB.x * w0B.x + vB.y * w0B.y + vB.z * w0B.z + vB.w * w0B.w;
    float p1 = vA.x * w1A.x + vA.y * w1A.y + vA.z * w1A.z + vA.w * w1A.w
             + vB.x * w1B.x + vB.y * w1B.y + vB.z * w1B.z + vB.w * w1B.w;
    #pragma unroll
    for (int o = 32; o > 0; o >>= 1) { p0 += __shfl_xor(p0, o); p1 += __shfl_xor(p1, o); }
    if (lane == 0) { part[wv][m][0] = p0; part[wv][m][1] = p1; }
  }
  __syncthreads();
  if (tid < 128) {
    const int hH = tid >> 6, m = tid & 63;
    float s = 0.f;
    #pragma unroll
    for (int i = 0; i < 8; ++i) s += part[i][m][hH];
    atomicAdd(out + OFF_RVS + ((size_t)b * HRD + hH) * MD + m, s);
  }
}

// ---------------------------------------------------------------------------
extern "C" void kernel_launch(void* const* d_in, const int* in_sizes, int n_in,
                              void* d_out, int out_size, void* d_ws, size_t ws_size,
                              hipStream_t stream) {
  const float* inputs    = (const float*)d_in[0];
  const float* memory    = (const float*)d_in[1];
  const float* read_w    = (const float*)d_in[2];
  const float* write_w   = (const float*)d_in[3];
  const float* h         = (const float*)d_in[4];
  const float* c         = (const float*)d_in[5];
  const float* read_vecs = (const float*)d_in[6];
  const float* W_ih      = (const float*)d_in[7];
  const float* W_hh      = (const float*)d_in[8];
  const float* b_lstm    = (const float*)d_in[9];
  const float* W_int     = (const float*)d_in[10];
  const float* b_int     = (const float*)d_in[11];
  const float* W_out     = (const float*)d_in[12];
  const float* b_out     = (const float*)d_in[13];
  float* out = (float*)d_out;
  float* ws  = (float*)d_ws;

  hipLaunchKernelGGL(k_small, dim3(BB), dim3(256), 0, stream,
                     inputs, read_vecs, h, c, W_ih, W_hh, b_lstm, W_int, b_int,
                     W_out, b_out, out, ws);
  hipLaunchKernelGGL(k_wsim, dim3(4, BB), dim3(512), 0, stream, memory, ws);
  hipLaunchKernelGGL(k_wsharp, dim3(AD / 1024, BB), dim3(256), 0, stream, write_w, out, ws);
  hipLaunchKernelGGL(k_update, dim3(4, BB), dim3(512), 0, stream, memory, out, ws);
  hipLaunchKernelGGL(k_rsharp, dim3(AD / 1024, BB, HRD), dim3(256), 0, stream, read_w, out, ws);
  hipLaunchKernelGGL(k_rv, dim3(4, BB), dim3(512), 0, stream, out, ws);
}

// Round 4
// 659.425 us; speedup vs baseline: 1.6471x; 1.6471x over previous
//
#include <hip/hip_runtime.h>
#include <math.h>

#define BB 64
#define ID 10
#define MD 64
#define AD 16384
#define HCD 256
#define HRD 2
#define OD 8
#define PD 338
#define LIN 138
#define EPSF 1e-8f

// ---- output layout (floats), reference return order:
// logits[B,O], mem_new[B,M,A], rvs[B,HR,M], rws[B,HR,A], w_wr[B,A], h_new[B,HC], c_new[B,HC]
static constexpr size_t OFF_LOGITS = 0;
static constexpr size_t OFF_MEM = (size_t)BB * OD;
static constexpr size_t OFF_RVS = OFF_MEM + (size_t)BB * MD * AD;
static constexpr size_t OFF_RWS = OFF_RVS + (size_t)BB * HRD * MD;
static constexpr size_t OFF_WWR = OFF_RWS + (size_t)BB * HRD * AD;
static constexpr size_t OFF_H   = OFF_WWR + (size_t)BB * AD;
static constexpr size_t OFF_C   = OFF_H + (size_t)BB * HCD;

// ---- workspace layout (floats)
// per-b params (stride 384): [0:64) kn_w  [64:128) erase  [128:192) add
// [192:256) kn_r0  [256:320) kn_r1
// [320]=beta_w [321]=g_w [322..324]=s_w [325]=gamma_w
// [326..331]=read0 (beta,g,s0,s1,s2,gamma)  [332..337]=read1
static constexpr size_t PAR = 0;
static constexpr size_t PAR_STR = 384;
static constexpr size_t EW   = PAR + (size_t)BB * PAR_STR;
static constexpr size_t ER   = EW + (size_t)BB * AD;
static constexpr size_t SUMS = ER + (size_t)2 * BB * AD;   // per-b 8 slots (512 total)
// small-chain scratch (channel-major, batch in lanes):
static constexpr size_t XT0  = SUMS + 512;                 // [LIN][64]  x transposed
static constexpr size_t HTO0 = XT0 + (size_t)LIN * 64;     // [256][64]  old h transposed
static constexpr size_t HTN0 = HTO0 + (size_t)HCD * 64;    // [256][64]  new h transposed
static constexpr size_t G0   = HTN0 + (size_t)HCD * 64;    // [1024][64] gates
static constexpr size_t P0   = G0 + (size_t)4 * HCD * 64;  // [338][64]  interface vec

__device__ __forceinline__ float sigmoidf_(float x) { return 1.f / (1.f + expf(-x)); }
__device__ __forceinline__ float softplusf_(float x) { return x > 20.f ? x : log1pf(expf(x)); }

// ---------------------------------------------------------------------------
// K0: transpose x,h into channel-major; zero rvs + sums
// ---------------------------------------------------------------------------
__global__ __launch_bounds__(256) void k_prep(
    const float* __restrict__ inputs, const float* __restrict__ read_vecs,
    const float* __restrict__ h, float* __restrict__ out, float* __restrict__ ws)
{
  const int i = blockIdx.x * 256 + threadIdx.x;
  if (i < 8832) {                                   // XT[k][b]
    const int k = i >> 6, b = i & 63;
    ws[XT0 + i] = (k < ID) ? inputs[(size_t)b * ID + k]
                           : read_vecs[(size_t)b * HRD * MD + (k - ID)];
  } else if (i < 25216) {                           // HTO[k][b]
    const int j = i - 8832, k = j >> 6, b = j & 63;
    ws[HTO0 + j] = h[(size_t)b * HCD + k];
  } else if (i < 33408) {                           // zero rvs
    out[OFF_RVS + (i - 25216)] = 0.f;
  } else if (i < 33920) {                           // zero sums
    ws[SUMS + (i - 33408)] = 0.f;
  }
}

// ---------------------------------------------------------------------------
// K1: gates GEMM — wave = output channel j (1024 waves), lane = batch
// ---------------------------------------------------------------------------
__global__ __launch_bounds__(256) void k_gates(
    const float* __restrict__ W_ih, const float* __restrict__ W_hh,
    const float* __restrict__ b_lstm, float* __restrict__ ws)
{
  const int lane = threadIdx.x & 63, wv = threadIdx.x >> 6;
  const int j = blockIdx.x * 4 + wv;
  const float* xt = ws + XT0 + lane;
  const float* ht = ws + HTO0 + lane;
  float acc = 0.f;
  const float* wr = W_ih + (size_t)j * LIN;
  #pragma unroll 2
  for (int k = 0; k < LIN; ++k) acc += wr[k] * xt[(size_t)k * 64];
  const float* wh = W_hh + (size_t)j * HCD;
  #pragma unroll
  for (int k4 = 0; k4 < HCD / 4; ++k4) {
    float4 w4 = *(const float4*)(wh + k4 * 4);
    acc += w4.x * ht[(size_t)(k4 * 4 + 0) * 64];
    acc += w4.y * ht[(size_t)(k4 * 4 + 1) * 64];
    acc += w4.z * ht[(size_t)(k4 * 4 + 2) * 64];
    acc += w4.w * ht[(size_t)(k4 * 4 + 3) * 64];
  }
  ws[G0 + (size_t)j * 64 + lane] = acc + b_lstm[j];
}

// ---------------------------------------------------------------------------
// K2: LSTM elementwise; writes h_new/c_new outputs + transposed h_new
// ---------------------------------------------------------------------------
__global__ __launch_bounds__(256) void k_lstm(
    const float* __restrict__ c, float* __restrict__ out, float* __restrict__ ws)
{
  const int t = threadIdx.x;
  const int ch = blockIdx.x * 4 + (t >> 6), b = t & 63;
  const float ig = ws[G0 + (size_t)ch * 64 + b];
  const float fg = ws[G0 + (size_t)(ch + 256) * 64 + b];
  const float gg = ws[G0 + (size_t)(ch + 512) * 64 + b];
  const float og = ws[G0 + (size_t)(ch + 768) * 64 + b];
  const float cv = c[(size_t)b * HCD + ch];
  const float cn = sigmoidf_(fg) * cv + sigmoidf_(ig) * tanhf(gg);
  const float hn = sigmoidf_(og) * tanhf(cn);
  out[OFF_C + (size_t)b * HCD + ch] = cn;
  out[OFF_H + (size_t)b * HCD + ch] = hn;
  ws[HTN0 + (size_t)ch * 64 + b] = hn;
}

// ---------------------------------------------------------------------------
// K3: interface GEMM (p, 338 ch) + logits (8 ch) — wave = channel, lane = batch
// ---------------------------------------------------------------------------
__global__ __launch_bounds__(256) void k_int(
    const float* __restrict__ W_int, const float* __restrict__ b_int,
    const float* __restrict__ W_out, const float* __restrict__ b_out,
    float* __restrict__ out, float* __restrict__ ws)
{
  const int lane = threadIdx.x & 63, wv = threadIdx.x >> 6;
  const int j = blockIdx.x * 4 + wv;
  if (j >= PD + OD) return;
  const bool isp = (j < PD);
  const float* wr = isp ? (W_int + (size_t)j * HCD) : (W_out + (size_t)(j - PD) * HCD);
  const float* ht = ws + HTN0 + lane;
  float acc = 0.f;
  #pragma unroll
  for (int k4 = 0; k4 < HCD / 4; ++k4) {
    float4 w4 = *(const float4*)(wr + k4 * 4);
    acc += w4.x * ht[(size_t)(k4 * 4 + 0) * 64];
    acc += w4.y * ht[(size_t)(k4 * 4 + 1) * 64];
    acc += w4.z * ht[(size_t)(k4 * 4 + 2) * 64];
    acc += w4.w * ht[(size_t)(k4 * 4 + 3) * 64];
  }
  if (isp) ws[P0 + (size_t)j * 64 + lane] = acc + b_int[j];
  else     out[OFF_LOGITS + (size_t)lane * OD + (j - PD)] = acc + b_out[j - PD];
}

// ---------------------------------------------------------------------------
// K4: per-batch param processing (reads P[ch][b], writes par block)
// ---------------------------------------------------------------------------
__global__ __launch_bounds__(256) void k_params(float* __restrict__ ws)
{
  const int b = blockIdx.x;
  const int t = threadIdx.x;
  const int lane = t & 63, wv = t >> 6;
  const float* P = ws + P0 + b;                 // P(i) = P[i*64]
  float* par = ws + PAR + (size_t)b * PAR_STR;

  if (wv < 3) {
    const int base = (wv == 0) ? 140 : (wv - 1) * 70;
    const int slot = (wv == 0) ? 0 : (192 + (wv - 1) * 64);
    float kv = P[(size_t)(base + lane) * 64];
    float ss = kv * kv;
    #pragma unroll
    for (int o = 32; o > 0; o >>= 1) ss += __shfl_xor(ss, o);
    par[slot + lane] = kv / (sqrtf(ss) + EPSF);
    if (lane == 0) {
      const int sb = (wv == 0) ? 320 : (326 + (wv - 1) * 6);
      float beta = softplusf_(P[(size_t)(base + 64) * 64]);
      float g = sigmoidf_(P[(size_t)(base + 65) * 64]);
      float s0 = P[(size_t)(base + 66) * 64];
      float s1 = P[(size_t)(base + 67) * 64];
      float s2 = P[(size_t)(base + 68) * 64];
      float mx = fmaxf(s0, fmaxf(s1, s2));
      float e0 = expf(s0 - mx), e1 = expf(s1 - mx), e2 = expf(s2 - mx);
      float inv = 1.f / (e0 + e1 + e2);
      float gamma = 1.f + softplusf_(P[(size_t)(base + 69) * 64]);
      par[sb + 0] = beta; par[sb + 1] = g;
      par[sb + 2] = e0 * inv; par[sb + 3] = e1 * inv; par[sb + 4] = e2 * inv;
      par[sb + 5] = gamma;
    }
  } else {
    par[64 + lane] = sigmoidf_(P[(size_t)(210 + lane) * 64]);   // erase
    par[128 + lane] = P[(size_t)(274 + lane) * 64];             // add
  }
}

// ---------------------------------------------------------------------------
// Sweep geometry (UNCHANGED from round 3): grid (4, B), 512 threads. Block q
// owns columns [q*4096,(q+1)*4096): thread owns float4 at c0 = q*4096 + tid*4
// and c1 = c0 + 2048.
// ---------------------------------------------------------------------------

// K5: write-head content sim over pre-update memory -> e = exp(beta*(sim-1))
__global__ __launch_bounds__(512) void k_wsim(const float* __restrict__ mem,
                                              float* __restrict__ ws)
{
  const int b = blockIdx.y, tid = threadIdx.x, q = blockIdx.x;
  const float* par = ws + PAR + (size_t)b * PAR_STR;
  __shared__ float kn[MD];
  if (tid < MD) kn[tid] = par[tid];
  __syncthreads();

  const size_t c0 = (size_t)q * 4096 + (size_t)tid * 4;
  const size_t c1 = c0 + 2048;
  const float* mb = mem + (size_t)b * MD * AD;

  float4 sA = {0,0,0,0}, sB = {0,0,0,0}, dA = {0,0,0,0}, dB = {0,0,0,0};
  #pragma unroll 4
  for (int m = 0; m < MD; ++m) {
    float4 vA = *(const float4*)(mb + (size_t)m * AD + c0);
    float4 vB = *(const float4*)(mb + (size_t)m * AD + c1);
    float kv = kn[m];
    sA.x += vA.x * vA.x; sA.y += vA.y * vA.y; sA.z += vA.z * vA.z; sA.w += vA.w * vA.w;
    sB.x += vB.x * vB.x; sB.y += vB.y * vB.y; sB.z += vB.z * vB.z; sB.w += vB.w * vB.w;
    dA.x += kv * vA.x;  dA.y += kv * vA.y;  dA.z += kv * vA.z;  dA.w += kv * vA.w;
    dB.x += kv * vB.x;  dB.y += kv * vB.y;  dB.z += kv * vB.z;  dB.w += kv * vB.w;
  }
  const float beta = par[320];
  float4 eA, eB;
  eA.x = expf(beta * (dA.x / (sqrtf(sA.x) + EPSF) - 1.f));
  eA.y = expf(beta * (dA.y / (sqrtf(sA.y) + EPSF) - 1.f));
  eA.z = expf(beta * (dA.z / (sqrtf(sA.z) + EPSF) - 1.f));
  eA.w = expf(beta * (dA.w / (sqrtf(sA.w) + EPSF) - 1.f));
  eB.x = expf(beta * (dB.x / (sqrtf(sB.x) + EPSF) - 1.f));
  eB.y = expf(beta * (dB.y / (sqrtf(sB.y) + EPSF) - 1.f));
  eB.z = expf(beta * (dB.z / (sqrtf(sB.z) + EPSF) - 1.f));
  eB.w = expf(beta * (dB.w / (sqrtf(sB.w) + EPSF) - 1.f));
  *(float4*)(ws + EW + (size_t)b * AD + c0) = eA;
  *(float4*)(ws + EW + (size_t)b * AD + c1) = eB;

  float s = eA.x + eA.y + eA.z + eA.w + eB.x + eB.y + eB.z + eB.w;
  #pragma unroll
  for (int o = 32; o > 0; o >>= 1) s += __shfl_xor(s, o);
  __shared__ float red[8];
  if ((tid & 63) == 0) red[tid >> 6] = s;
  __syncthreads();
  if (tid == 0) {
    float tot = 0.f;
    #pragma unroll
    for (int i = 0; i < 8; ++i) tot += red[i];
    atomicAdd(ws + SUMS + (size_t)b * 8 + 0, tot);
  }
}

// K6: write head: interpolate + circular shift + sharpen -> wp (unnormalized)
__global__ __launch_bounds__(256) void k_wsharp(const float* __restrict__ write_w,
                                                float* __restrict__ out,
                                                float* __restrict__ ws)
{
  const int b = blockIdx.y;
  const int tid = threadIdx.x;
  const int a0 = blockIdx.x * 1024 + tid * 4;
  const float* par = ws + PAR + (size_t)b * PAR_STR;
  const float g = par[321], s0 = par[322], s1 = par[323], s2 = par[324], gamma = par[325];
  const float inv_se = 1.f / ws[SUMS + (size_t)b * 8 + 0];
  const float* e = ws + EW + (size_t)b * AD;
  const float* wprev = write_w + (size_t)b * AD;

  float4 ec = *(const float4*)(e + a0);
  float4 wc = *(const float4*)(wprev + a0);
  const int am1 = (a0 - 1) & (AD - 1), ap4 = (a0 + 4) & (AD - 1);
  float ev[6] = {e[am1], ec.x, ec.y, ec.z, ec.w, e[ap4]};
  float wvv[6] = {wprev[am1], wc.x, wc.y, wc.z, wc.w, wprev[ap4]};
  float wg[6];
  #pragma unroll
  for (int i = 0; i < 6; ++i) wg[i] = g * ev[i] * inv_se + (1.f - g) * wvv[i];

  float4 wp;
  wp.x = powf(s0 * wg[2] + s1 * wg[1] + s2 * wg[0] + EPSF, gamma);
  wp.y = powf(s0 * wg[3] + s1 * wg[2] + s2 * wg[1] + EPSF, gamma);
  wp.z = powf(s0 * wg[4] + s1 * wg[3] + s2 * wg[2] + EPSF, gamma);
  wp.w = powf(s0 * wg[5] + s1 * wg[4] + s2 * wg[3] + EPSF, gamma);
  *(float4*)(out + OFF_WWR + (size_t)b * AD + a0) = wp;

  float s = wp.x + wp.y + wp.z + wp.w;
  #pragma unroll
  for (int o = 32; o > 0; o >>= 1) s += __shfl_xor(s, o);
  __shared__ float red[4];
  if ((tid & 63) == 0) red[tid >> 6] = s;
  __syncthreads();
  if (tid == 0) atomicAdd(ws + SUMS + (size_t)b * 8 + 1, red[0] + red[1] + red[2] + red[3]);
}

// K7: normalize w_wr, memory update, read-head sims over mem_new (fused)
__global__ __launch_bounds__(512) void k_update(const float* __restrict__ mem,
                                                float* __restrict__ out,
                                                float* __restrict__ ws)
{
  const int b = blockIdx.y, tid = threadIdx.x, q = blockIdx.x;
  const float* par = ws + PAR + (size_t)b * PAR_STR;
  __shared__ float se[MD], sa[MD], sk0[MD], sk1[MD];
  if (tid < MD) {
    se[tid] = par[64 + tid]; sa[tid] = par[128 + tid];
    sk0[tid] = par[192 + tid]; sk1[tid] = par[256 + tid];
  }
  __syncthreads();

  const size_t c0 = (size_t)q * 4096 + (size_t)tid * 4;
  const size_t c1 = c0 + 2048;
  const float invw = 1.f / (ws[SUMS + (size_t)b * 8 + 1] + EPSF);
  float* wwr = out + OFF_WWR + (size_t)b * AD;
  float4 wA = *(float4*)(wwr + c0);
  float4 wB = *(float4*)(wwr + c1);
  wA.x *= invw; wA.y *= invw; wA.z *= invw; wA.w *= invw;
  wB.x *= invw; wB.y *= invw; wB.z *= invw; wB.w *= invw;
  *(float4*)(wwr + c0) = wA;
  *(float4*)(wwr + c1) = wB;

  const float* mb = mem + (size_t)b * MD * AD;
  float* nb = out + OFF_MEM + (size_t)b * MD * AD;
  float4 sA = {0,0,0,0}, sB = {0,0,0,0};
  float4 d0A = {0,0,0,0}, d0B = {0,0,0,0}, d1A = {0,0,0,0}, d1B = {0,0,0,0};
  #pragma unroll 4
  for (int m = 0; m < MD; ++m) {
    float4 vA = *(const float4*)(mb + (size_t)m * AD + c0);
    float4 vB = *(const float4*)(mb + (size_t)m * AD + c1);
    float er = se[m], ad = sa[m], k0 = sk0[m], k1 = sk1[m];
    float4 nA, nB;
    nA.x = vA.x * (1.f - er * wA.x) + ad * wA.x;
    nA.y = vA.y * (1.f - er * wA.y) + ad * wA.y;
    nA.z = vA.z * (1.f - er * wA.z) + ad * wA.z;
    nA.w = vA.w * (1.f - er * wA.w) + ad * wA.w;
    nB.x = vB.x * (1.f - er * wB.x) + ad * wB.x;
    nB.y = vB.y * (1.f - er * wB.y) + ad * wB.y;
    nB.z = vB.z * (1.f - er * wB.z) + ad * wB.z;
    nB.w = vB.w * (1.f - er * wB.w) + ad * wB.w;
    *(float4*)(nb + (size_t)m * AD + c0) = nA;
    *(float4*)(nb + (size_t)m * AD + c1) = nB;
    sA.x += nA.x * nA.x; sA.y += nA.y * nA.y; sA.z += nA.z * nA.z; sA.w += nA.w * nA.w;
    sB.x += nB.x * nB.x; sB.y += nB.y * nB.y; sB.z += nB.z * nB.z; sB.w += nB.w * nB.w;
    d0A.x += k0 * nA.x; d0A.y += k0 * nA.y; d0A.z += k0 * nA.z; d0A.w += k0 * nA.w;
    d0B.x += k0 * nB.x; d0B.y += k0 * nB.y; d0B.z += k0 * nB.z; d0B.w += k0 * nB.w;
    d1A.x += k1 * nA.x; d1A.y += k1 * nA.y; d1A.z += k1 * nA.z; d1A.w += k1 * nA.w;
    d1B.x += k1 * nB.x; d1B.y += k1 * nB.y; d1B.z += k1 * nB.z; d1B.w += k1 * nB.w;
  }
  const float b0 = par[326], b1 = par[332];
  float4 e0A, e0B, e1A, e1B;
  e0A.x = expf(b0 * (d0A.x / (sqrtf(sA.x) + EPSF) - 1.f));
  e0A.y = expf(b0 * (d0A.y / (sqrtf(sA.y) + EPSF) - 1.f));
  e0A.z = expf(b0 * (d0A.z / (sqrtf(sA.z) + EPSF) - 1.f));
  e0A.w = expf(b0 * (d0A.w / (sqrtf(sA.w) + EPSF) - 1.f));
  e0B.x = expf(b0 * (d0B.x / (sqrtf(sB.x) + EPSF) - 1.f));
  e0B.y = expf(b0 * (d0B.y / (sqrtf(sB.y) + EPSF) - 1.f));
  e0B.z = expf(b0 * (d0B.z / (sqrtf(sB.z) + EPSF) - 1.f));
  e0B.w = expf(b0 * (d0B.w / (sqrtf(sB.w) + EPSF) - 1.f));
  e1A.x = expf(b1 * (d1A.x / (sqrtf(sA.x) + EPSF) - 1.f));
  e1A.y = expf(b1 * (d1A.y / (sqrtf(sA.y) + EPSF) - 1.f));
  e1A.z = expf(b1 * (d1A.z / (sqrtf(sA.z) + EPSF) - 1.f));
  e1A.w = expf(b1 * (d1A.w / (sqrtf(sA.w) + EPSF) - 1.f));
  e1B.x = expf(b1 * (d1B.x / (sqrtf(sB.x) + EPSF) - 1.f));
  e1B.y = expf(b1 * (d1B.y / (sqrtf(sB.y) + EPSF) - 1.f));
  e1B.z = expf(b1 * (d1B.z / (sqrtf(sB.z) + EPSF) - 1.f));
  e1B.w = expf(b1 * (d1B.w / (sqrtf(sB.w) + EPSF) - 1.f));
  float* er0 = ws + ER + ((size_t)0 * BB + b) * AD;
  float* er1 = ws + ER + ((size_t)1 * BB + b) * AD;
  *(float4*)(er0 + c0) = e0A; *(float4*)(er0 + c1) = e0B;
  *(float4*)(er1 + c0) = e1A; *(float4*)(er1 + c1) = e1B;

  float p0 = e0A.x + e0A.y + e0A.z + e0A.w + e0B.x + e0B.y + e0B.z + e0B.w;
  float p1 = e1A.x + e1A.y + e1A.z + e1A.w + e1B.x + e1B.y + e1B.z + e1B.w;
  #pragma unroll
  for (int o = 32; o > 0; o >>= 1) { p0 += __shfl_xor(p0, o); p1 += __shfl_xor(p1, o); }
  __shared__ float red[16];
  const int lane = tid & 63, wv = tid >> 6;
  if (lane == 0) { red[wv] = p0; red[8 + wv] = p1; }
  __syncthreads();
  if (tid == 0) {
    float t0 = 0.f, t1 = 0.f;
    #pragma unroll
    for (int i = 0; i < 8; ++i) { t0 += red[i]; t1 += red[8 + i]; }
    atomicAdd(ws + SUMS + (size_t)b * 8 + 2, t0);
    atomicAdd(ws + SUMS + (size_t)b * 8 + 3, t1);
  }
}

// K8: read heads: interpolate + shift + sharpen -> wp into rws slot
__global__ __launch_bounds__(256) void k_rsharp(const float* __restrict__ read_w,
                                                float* __restrict__ out,
                                                float* __restrict__ ws)
{
  const int b = blockIdx.y;
  const int hH = blockIdx.z;
  const int tid = threadIdx.x;
  const int a0 = blockIdx.x * 1024 + tid * 4;
  const float* par = ws + PAR + (size_t)b * PAR_STR;
  const int sb = 326 + hH * 6;
  const float g = par[sb + 1], s0 = par[sb + 2], s1 = par[sb + 3], s2 = par[sb + 4], gamma = par[sb + 5];
  const float inv_se = 1.f / ws[SUMS + (size_t)b * 8 + 2 + hH];
  const float* e = ws + ER + ((size_t)hH * BB + b) * AD;
  const float* wprev = read_w + ((size_t)b * HRD + hH) * AD;

  float4 ec = *(const float4*)(e + a0);
  float4 wc = *(const float4*)(wprev + a0);
  const int am1 = (a0 - 1) & (AD - 1), ap4 = (a0 + 4) & (AD - 1);
  float ev[6] = {e[am1], ec.x, ec.y, ec.z, ec.w, e[ap4]};
  float wvv[6] = {wprev[am1], wc.x, wc.y, wc.z, wc.w, wprev[ap4]};
  float wg[6];
  #pragma unroll
  for (int i = 0; i < 6; ++i) wg[i] = g * ev[i] * inv_se + (1.f - g) * wvv[i];

  float4 wp;
  wp.x = powf(s0 * wg[2] + s1 * wg[1] + s2 * wg[0] + EPSF, gamma);
  wp.y = powf(s0 * wg[3] + s1 * wg[2] + s2 * wg[1] + EPSF, gamma);
  wp.z = powf(s0 * wg[4] + s1 * wg[3] + s2 * wg[2] + EPSF, gamma);
  wp.w = powf(s0 * wg[5] + s1 * wg[4] + s2 * wg[3] + EPSF, gamma);
  *(float4*)(out + OFF_RWS + ((size_t)b * HRD + hH) * AD + a0) = wp;

  float s = wp.x + wp.y + wp.z + wp.w;
  #pragma unroll
  for (int o = 32; o > 0; o >>= 1) s += __shfl_xor(s, o);
  __shared__ float red[4];
  if ((tid & 63) == 0) red[tid >> 6] = s;
  __syncthreads();
  if (tid == 0) atomicAdd(ws + SUMS + (size_t)b * 8 + 4 + hH, red[0] + red[1] + red[2] + red[3]);
}

// K9: normalize rws in place + read vectors (one pass over mem_new)
__global__ __launch_bounds__(512) void k_rv(float* __restrict__ out,
                                            const float* __restrict__ ws)
{
  const int b = blockIdx.y, tid = threadIdx.x, q = blockIdx.x;
  const size_t c0 = (size_t)q * 4096 + (size_t)tid * 4;
  const size_t c1 = c0 + 2048;
  const float inv0 = 1.f / (ws[SUMS + (size_t)b * 8 + 4] + EPSF);
  const float inv1 = 1.f / (ws[SUMS + (size_t)b * 8 + 5] + EPSF);

  float* r0 = out + OFF_RWS + ((size_t)b * HRD + 0) * AD;
  float* r1 = out + OFF_RWS + ((size_t)b * HRD + 1) * AD;
  float4 w0A = *(float4*)(r0 + c0), w0B = *(float4*)(r0 + c1);
  float4 w1A = *(float4*)(r1 + c0), w1B = *(float4*)(r1 + c1);
  w0A.x *= inv0; w0A.y *= inv0; w0A.z *= inv0; w0A.w *= inv0;
  w0B.x *= inv0; w0B.y *= inv0; w0B.z *= inv0; w0B.w *= inv0;
  w1A.x *= inv1; w1A.y *= inv1; w1A.z *= inv1; w1A.w *= inv1;
  w1B.x *= inv1; w1B.y *= inv1; w1B.z *= inv1; w1B.w *= inv1;
  *(float4*)(r0 + c0) = w0A; *(float4*)(r0 + c1) = w0B;
  *(float4*)(r1 + c0) = w1A; *(float4*)(r1 + c1) = w1B;

  const float* mn = out + OFF_MEM + (size_t)b * MD * AD;
  __shared__ float part[8][MD][2];
  const int lane = tid & 63, wv = tid >> 6;
  for (int m = 0; m < MD; ++m) {
    float4 vA = *(const float4*)(mn + (size_t)m * AD + c0);
    float4 vB = *(const float4*)(mn + (size_t)m * AD + c1);
    float p0 = vA.x * w0A.x + vA.y * w0A.y + vA.z * w0A.z + vA.w * w0A.w
             + vB.x * w0B.x + vB.y * w0B.y + vB.z * w0B.z + vB.w * w0B.w;
    float p1 = vA.x * w1A.x + vA.y * w1A.y + vA.z * w1A.z + vA.w * w1A.w
             + vB.x * w1B.x + vB.y * w1B.y + vB.z * w1B.z + vB.w * w1B.w;
    #pragma unroll
    for (int o = 32; o > 0; o >>= 1) { p0 += __shfl_xor(p0, o); p1 += __shfl_xor(p1, o); }
    if (lane == 0) { part[wv][m][0] = p0; part[wv][m][1] = p1; }
  }
  __syncthreads();
  if (tid < 128) {
    const int hH = tid >> 6, m = tid & 63;
    float s = 0.f;
    #pragma unroll
    for (int i = 0; i < 8; ++i) s += part[i][m][hH];
    atomicAdd(out + OFF_RVS + ((size_t)b * HRD + hH) * MD + m, s);
  }
}

// ---------------------------------------------------------------------------
extern "C" void kernel_launch(void* const* d_in, const int* in_sizes, int n_in,
                              void* d_out, int out_size, void* d_ws, size_t ws_size,
                              hipStream_t stream) {
  const float* inputs    = (const float*)d_in[0];
  const float* memory    = (const float*)d_in[1];
  const float* read_w    = (const float*)d_in[2];
  const float* write_w   = (const float*)d_in[3];
  const float* h         = (const float*)d_in[4];
  const float* c         = (const float*)d_in[5];
  const float* read_vecs = (const float*)d_in[6];
  const float* W_ih      = (const float*)d_in[7];
  const float* W_hh      = (const float*)d_in[8];
  const float* b_lstm    = (const float*)d_in[9];
  const float* W_int     = (const float*)d_in[10];
  const float* b_int     = (const float*)d_in[11];
  const float* W_out     = (const float*)d_in[12];
  const float* b_out     = (const float*)d_in[13];
  float* out = (float*)d_out;
  float* ws  = (float*)d_ws;

  hipLaunchKernelGGL(k_prep, dim3(133), dim3(256), 0, stream,
                     inputs, read_vecs, h, out, ws);
  hipLaunchKernelGGL(k_gates, dim3(256), dim3(256), 0, stream,
                     W_ih, W_hh, b_lstm, ws);
  hipLaunchKernelGGL(k_lstm, dim3(64), dim3(256), 0, stream, c, out, ws);
  hipLaunchKernelGGL(k_int, dim3(87), dim3(256), 0, stream,
                     W_int, b_int, W_out, b_out, out, ws);
  hipLaunchKernelGGL(k_params, dim3(64), dim3(256), 0, stream, ws);
  hipLaunchKernelGGL(k_wsim, dim3(4, BB), dim3(512), 0, stream, memory, ws);
  hipLaunchKernelGGL(k_wsharp, dim3(AD / 1024, BB), dim3(256), 0, stream, write_w, out, ws);
  hipLaunchKernelGGL(k_update, dim3(4, BB), dim3(512), 0, stream, memory, out, ws);
  hipLaunchKernelGGL(k_rsharp, dim3(AD / 1024, BB, HRD), dim3(256), 0, stream, read_w, out, ws);
  hipLaunchKernelGGL(k_rv, dim3(4, BB), dim3(512), 0, stream, out, ws);
}